// Round 7
// baseline (584.152 us; speedup 1.0000x reference)
//
#include <hip/hip_runtime.h>

// 3-layer GCN 2->16->16->1, N=250k, E=4M.
// Pipeline: pass A bins edges by src-tile (8192 nodes/tile) -> pass B bins
// the tile-ordered stream by dst-bucket (256 nodes). Pass B's per-(block,
// bucket) pre-reserved regions preserve input order, so each bucket's entry
// list is grouped by src-tile -> layer2's gather walks dh1 through an
// L2-resident moving window instead of random 16MB.
// Layers: one block per bucket, LDS accumulator, fused relu+transform;
// transforms commuted so layer1 gathers 8B rows and layer3 scalars.

constexpr int K    = 977;    // ceil(250000/256) dst buckets
constexpr int NPW  = 256;    // nodes per bucket
constexpr int G    = 256;    // binning blocks
constexpr int F    = 16;
constexpr int TILE = 8192;   // src nodes per tile (dh1 slice = 512KB)
constexpr int TMAX = 64;

// ---- pass A: bin by src-tile ------------------------------------------------

__global__ __launch_bounds__(1024) void k_acount(const int* __restrict__ src,
        int* __restrict__ acount, int E, int chunk, int T) {
    __shared__ int h[TMAX];
    if (threadIdx.x < TMAX) h[threadIdx.x] = 0;
    __syncthreads();
    int beg = blockIdx.x * chunk;
    int end = min(beg + chunk, E);
    for (int i = beg + threadIdx.x; i < end; i += 1024) {
        int s = __builtin_nontemporal_load(&src[i]);
        atomicAdd(&h[s / TILE], 1);
    }
    __syncthreads();
    if (threadIdx.x < T) acount[blockIdx.x * T + threadIdx.x] = h[threadIdx.x];
}

__global__ __launch_bounds__(256) void k_ascan(int* __restrict__ acount,
        int* __restrict__ tbase, int E, int T) {
    __shared__ int tot[TMAX];
    int t = threadIdx.x;
    if (t < T) {
        int s = 0;
        for (int b = 0; b < G; ++b) s += acount[b * T + t];
        tot[t] = s;
    }
    __syncthreads();
    if (t == 0) {                      // serial exclusive scan over <=64 tiles
        int run = 0;
        for (int q = 0; q < T; ++q) { int c = tot[q]; tot[q] = run; run += c; }
    }
    __syncthreads();
    if (t < T) {
        int run = tot[t];
        tbase[t] = run;
        for (int b = 0; b < G; ++b) {
            int c = acount[b * T + t];
            acount[b * T + t] = run;
            run += c;
        }
    }
    if (t == 0) tbase[T] = E;
}

// entA[pos] = (dst << 13) | (src & (TILE-1)); tile implicit from position.
__global__ __launch_bounds__(1024) void k_afill(const int* __restrict__ src,
        const int* __restrict__ dst, const int* __restrict__ abase,
        unsigned int* __restrict__ entA, int E, int chunk, int T) {
    __shared__ int cur[TMAX];
    if (threadIdx.x < T) cur[threadIdx.x] = abase[blockIdx.x * T + threadIdx.x];
    __syncthreads();
    int beg = blockIdx.x * chunk;
    int end = min(beg + chunk, E);
    for (int i = beg + threadIdx.x; i < end; i += 1024) {
        int s = __builtin_nontemporal_load(&src[i]);
        int d = __builtin_nontemporal_load(&dst[i]);
        int pos = atomicAdd(&cur[s / TILE], 1);
        entA[pos] = ((unsigned int)d << 13) | (unsigned int)(s & (TILE - 1));
    }
}

// ---- pass B: bin tile-ordered stream by dst-bucket --------------------------

__global__ __launch_bounds__(1024) void k_bcount(const unsigned int* __restrict__ entA,
        int* __restrict__ bcount, int E, int chunk) {
    __shared__ int h[K];
    for (int k = threadIdx.x; k < K; k += 1024) h[k] = 0;
    __syncthreads();
    int beg = blockIdx.x * chunk;
    int end = min(beg + chunk, E);
    for (int i = beg + threadIdx.x; i < end; i += 1024) {
        unsigned int v = __builtin_nontemporal_load(&entA[i]);
        atomicAdd(&h[(v >> 13) >> 8], 1);
    }
    __syncthreads();
    for (int k = threadIdx.x; k < K; k += 1024)
        bcount[blockIdx.x * K + k] = h[k];
}

__global__ __launch_bounds__(1024) void k_scan(int* __restrict__ bcount,
        int* __restrict__ colbase, int E) {
    __shared__ int tot[1024];
    int k = threadIdx.x;
    int s = 0;
    if (k < K) for (int b = 0; b < G; ++b) s += bcount[b * K + k];
    tot[k] = s;
    __syncthreads();
    for (int off = 1; off < 1024; off <<= 1) {
        int t = (k >= off) ? tot[k - off] : 0;
        __syncthreads();
        tot[k] += t;
        __syncthreads();
    }
    if (k < K) {
        int run = tot[k] - s;
        colbase[k] = run;
        for (int b = 0; b < G; ++b) {
            int t = bcount[b * K + k];
            bcount[b * K + k] = run;
            run += t;
        }
    }
    if (k == 0) colbase[K] = E;
}

// Reconstruct full src via the tile of position i (per-thread monotone walk).
__global__ __launch_bounds__(1024) void k_bfill(const unsigned int* __restrict__ entA,
        const int* __restrict__ tbase, const int* __restrict__ base,
        int* __restrict__ ent, int E, int chunk, int T) {
    __shared__ int cur[K];
    __shared__ int tb[TMAX + 1];
    for (int k = threadIdx.x; k < K; k += 1024)
        cur[k] = base[blockIdx.x * K + k];
    if (threadIdx.x <= T) tb[threadIdx.x] = tbase[threadIdx.x];
    __syncthreads();
    int beg = blockIdx.x * chunk;
    int end = min(beg + chunk, E);
    int t = 0;
    for (int i = beg + threadIdx.x; i < end; i += 1024) {
        while (i >= tb[t + 1]) ++t;
        unsigned int v = __builtin_nontemporal_load(&entA[i]);
        int d = (int)(v >> 13);
        int s = (t * TILE) + (int)(v & (TILE - 1));
        int pos = atomicAdd(&cur[d >> 8], 1);
        ent[pos] = (s << 8) | (d & 255);
    }
}

// ---- per-bucket degree + pre-scaled 2-wide input ----------------------------

__global__ __launch_bounds__(256) void k_prep(const int* __restrict__ ent,
        const int* __restrict__ colbase, const float* __restrict__ x,
        float* __restrict__ dinv, float* __restrict__ dx, int n) {
    __shared__ int h[NPW];
    h[threadIdx.x] = 0;
    __syncthreads();
    int beg = colbase[blockIdx.x], end = colbase[blockIdx.x + 1];
    for (int e = beg + threadIdx.x; e < end; e += 256) {
        int v = __builtin_nontemporal_load(&ent[e]);
        atomicAdd(&h[v & 255], 1);
    }
    __syncthreads();
    int i = (blockIdx.x << 8) + threadIdx.x;
    if (i < n) {
        float di = rsqrtf((float)h[threadIdx.x] + 1.0f);
        dinv[i] = di;
        float2 xv = reinterpret_cast<const float2*>(x)[i];
        reinterpret_cast<float2*>(dx)[i] = make_float2(di * xv.x, di * xv.y);
    }
}

// ---- layer 1: aggregate 2-wide dx, then (2->16) W1 + b1 + relu -------------

__global__ __launch_bounds__(512) void k_layer1(const int* __restrict__ ent,
        const int* __restrict__ colbase, const float* __restrict__ dinv,
        const float* __restrict__ dx, const float* __restrict__ W1,
        const float* __restrict__ b1, float* __restrict__ dh1, int n) {
    __shared__ float acc[NPW * 2];
    __shared__ float sW[32];
    __shared__ float sb[16];
    if (threadIdx.x < 32) sW[threadIdx.x] = W1[threadIdx.x];
    if (threadIdx.x >= 32 && threadIdx.x < 48) sb[threadIdx.x - 32] = b1[threadIdx.x - 32];
    for (int t = threadIdx.x; t < NPW * 2; t += 512) acc[t] = 0.0f;
    __syncthreads();
    int beg = colbase[blockIdx.x], end = colbase[blockIdx.x + 1];
    int e = beg + threadIdx.x;
    for (; e + 512 < end; e += 1024) {
        int v0 = __builtin_nontemporal_load(&ent[e]);
        int v1 = __builtin_nontemporal_load(&ent[e + 512]);
        float2 a0 = reinterpret_cast<const float2*>(dx)[v0 >> 8];
        float2 a1 = reinterpret_cast<const float2*>(dx)[v1 >> 8];
        atomicAdd(&acc[(v0 & 255) * 2 + 0], a0.x);
        atomicAdd(&acc[(v0 & 255) * 2 + 1], a0.y);
        atomicAdd(&acc[(v1 & 255) * 2 + 0], a1.x);
        atomicAdd(&acc[(v1 & 255) * 2 + 1], a1.y);
    }
    if (e < end) {
        int v = __builtin_nontemporal_load(&ent[e]);
        float2 a = reinterpret_cast<const float2*>(dx)[v >> 8];
        atomicAdd(&acc[(v & 255) * 2 + 0], a.x);
        atomicAdd(&acc[(v & 255) * 2 + 1], a.y);
    }
    __syncthreads();
    int r = threadIdx.x;
    if (r < NPW) {
        int i = (blockIdx.x << 8) + r;
        if (i < n) {
            float di = dinv[i];
            float2 ds = reinterpret_cast<const float2*>(dx)[i];
            float a0 = di * (acc[r * 2 + 0] + ds.x);
            float a1 = di * (acc[r * 2 + 1] + ds.y);
            float4* orow = reinterpret_cast<float4*>(dh1 + (size_t)i * F);
#pragma unroll
            for (int q = 0; q < 4; ++q) {
                float4 o;
                o.x = di * fmaxf(a0 * sW[4*q+0] + a1 * sW[16 + 4*q+0] + sb[4*q+0], 0.0f);
                o.y = di * fmaxf(a0 * sW[4*q+1] + a1 * sW[16 + 4*q+1] + sb[4*q+1], 0.0f);
                o.z = di * fmaxf(a0 * sW[4*q+2] + a1 * sW[16 + 4*q+2] + sb[4*q+2], 0.0f);
                o.w = di * fmaxf(a0 * sW[4*q+3] + a1 * sW[16 + 4*q+3] + sb[4*q+3], 0.0f);
                orow[q] = o;
            }
        }
    }
}

// ---- layer 2: aggregate 16-wide dh1 (tile-ordered gather); then
// h2 = relu(agg@W2 + b2); dxw3 = di*(h2.W3). 256 thr: 4 lanes/edge, 4-unroll.

__global__ __launch_bounds__(256) void k_layer2(const int* __restrict__ ent,
        const int* __restrict__ colbase, const float* __restrict__ dinv,
        const float* __restrict__ dh1, const float* __restrict__ W2,
        const float* __restrict__ b2, const float* __restrict__ W3,
        float* __restrict__ dxw3, int n) {
    __shared__ float acc[NPW * 17];
    __shared__ float sW2[256];
    __shared__ float sW3[16];
    __shared__ float sb[16];
    int tid = threadIdx.x;
    sW2[tid] = W2[tid];
    if (tid < 16) sW3[tid] = W3[tid];
    else if (tid < 32) sb[tid - 16] = b2[tid - 16];
    for (int t = tid; t < NPW * 17; t += 256) acc[t] = 0.0f;
    __syncthreads();
    int beg = colbase[blockIdx.x], end = colbase[blockIdx.x + 1];
    int q4 = (tid & 3) * 4;
    int eg = tid >> 2;                 // 64 edge slots
    int e = beg + eg;
    for (; e + 192 < end; e += 256) {
        int v0 = __builtin_nontemporal_load(&ent[e]);
        int v1 = __builtin_nontemporal_load(&ent[e + 64]);
        int v2 = __builtin_nontemporal_load(&ent[e + 128]);
        int v3 = __builtin_nontemporal_load(&ent[e + 192]);
        float4 r0 = *reinterpret_cast<const float4*>(dh1 + (size_t)(v0 >> 8) * F + q4);
        float4 r1 = *reinterpret_cast<const float4*>(dh1 + (size_t)(v1 >> 8) * F + q4);
        float4 r2 = *reinterpret_cast<const float4*>(dh1 + (size_t)(v2 >> 8) * F + q4);
        float4 r3 = *reinterpret_cast<const float4*>(dh1 + (size_t)(v3 >> 8) * F + q4);
        int b0 = (v0 & 255) * 17 + q4;
        int b1_ = (v1 & 255) * 17 + q4;
        int b2_ = (v2 & 255) * 17 + q4;
        int b3_ = (v3 & 255) * 17 + q4;
        atomicAdd(&acc[b0 + 0], r0.x); atomicAdd(&acc[b0 + 1], r0.y);
        atomicAdd(&acc[b0 + 2], r0.z); atomicAdd(&acc[b0 + 3], r0.w);
        atomicAdd(&acc[b1_ + 0], r1.x); atomicAdd(&acc[b1_ + 1], r1.y);
        atomicAdd(&acc[b1_ + 2], r1.z); atomicAdd(&acc[b1_ + 3], r1.w);
        atomicAdd(&acc[b2_ + 0], r2.x); atomicAdd(&acc[b2_ + 1], r2.y);
        atomicAdd(&acc[b2_ + 2], r2.z); atomicAdd(&acc[b2_ + 3], r2.w);
        atomicAdd(&acc[b3_ + 0], r3.x); atomicAdd(&acc[b3_ + 1], r3.y);
        atomicAdd(&acc[b3_ + 2], r3.z); atomicAdd(&acc[b3_ + 3], r3.w);
    }
    for (; e < end; e += 64) {
        int v = __builtin_nontemporal_load(&ent[e]);
        float4 r = *reinterpret_cast<const float4*>(dh1 + (size_t)(v >> 8) * F + q4);
        int b0 = (v & 255) * 17 + q4;
        atomicAdd(&acc[b0 + 0], r.x); atomicAdd(&acc[b0 + 1], r.y);
        atomicAdd(&acc[b0 + 2], r.z); atomicAdd(&acc[b0 + 3], r.w);
    }
    __syncthreads();
    int r = tid;
    {
        int i = (blockIdx.x << 8) + r;
        if (i < n) {
            float di = dinv[i];
            const float* dh = dh1 + (size_t)i * F;
            float a[16];
#pragma unroll
            for (int q = 0; q < 16; ++q) a[q] = di * (acc[r * 17 + q] + dh[q]);
            float sum = 0.0f;
#pragma unroll
            for (int c = 0; c < 16; ++c) {
                float h = sb[c];
#pragma unroll
                for (int q = 0; q < 16; ++q) h += a[q] * sW2[q * 16 + c];
                sum += fmaxf(h, 0.0f) * sW3[c];
            }
            dxw3[i] = di * sum;
        }
    }
}

// ---- layer 3 aggregation (scalar) -> out ------------------------------------

__global__ __launch_bounds__(512) void k_out(const int* __restrict__ ent,
        const int* __restrict__ colbase, const float* __restrict__ dinv,
        const float* __restrict__ dxw3, const float* __restrict__ b3,
        float* __restrict__ out, int n) {
    __shared__ float acc[NPW];
    for (int t = threadIdx.x; t < NPW; t += 512) acc[t] = 0.0f;
    __syncthreads();
    int beg = colbase[blockIdx.x], end = colbase[blockIdx.x + 1];
    int e = beg + threadIdx.x;
    for (; e + 512 < end; e += 1024) {
        int v0 = __builtin_nontemporal_load(&ent[e]);
        int v1 = __builtin_nontemporal_load(&ent[e + 512]);
        float s0 = dxw3[v0 >> 8];
        float s1 = dxw3[v1 >> 8];
        atomicAdd(&acc[v0 & 255], s0);
        atomicAdd(&acc[v1 & 255], s1);
    }
    if (e < end) {
        int v = __builtin_nontemporal_load(&ent[e]);
        atomicAdd(&acc[v & 255], dxw3[v >> 8]);
    }
    __syncthreads();
    int r = threadIdx.x;
    if (r < NPW) {
        int i = (blockIdx.x << 8) + r;
        if (i < n) out[i] = dinv[i] * (acc[r] + dxw3[i]) + b3[0];
    }
}

// ---- launch -----------------------------------------------------------------

extern "C" void kernel_launch(void* const* d_in, const int* in_sizes, int n_in,
                              void* d_out, int out_size, void* d_ws, size_t ws_size,
                              hipStream_t stream) {
    const float* x  = (const float*)d_in[0];
    const int*   ei = (const int*)d_in[1];
    const float* W1 = (const float*)d_in[2];
    const float* b1 = (const float*)d_in[3];
    const float* W2 = (const float*)d_in[4];
    const float* b2 = (const float*)d_in[5];
    const float* W3 = (const float*)d_in[6];
    const float* b3 = (const float*)d_in[7];

    const int n = in_sizes[0] / 2;   // [n,2]
    const int E = in_sizes[1] / 2;   // [2,E]
    const int* src = ei;
    const int* dst = ei + E;
    const int T = (n + TILE - 1) / TILE;   // 31 src tiles

    char* w = (char*)d_ws;
    int*   ent     = (int*)w;                    w += (size_t)E * 4;          // 16MB
    int*   bcount  = (int*)w;                    w += (size_t)G * K * 4;      // ~1MB
    int*   acount  = (int*)w;                    w += (size_t)G * TMAX * 4;   // 64KB
    int*   colbase = (int*)w;                    w += (size_t)(K + 1) * 4;
    int*   tbase   = (int*)w;                    w += (size_t)(TMAX + 1) * 4;
    w = (char*)(((uintptr_t)w + 15) & ~(uintptr_t)15);
    // pool: entA (16MB, binning-time) aliases dinv/dx/dh1 (layer-time)
    char* pool = w;
    unsigned int* entA = (unsigned int*)pool;                                 // 16MB
    float* dinv    = (float*)pool;               pool += (size_t)n * 4;       // 1MB
    float* dx      = (float*)pool;               pool += (size_t)n * 2 * 4;   // 2MB
    float* dh1     = (float*)pool;               pool += (size_t)n * F * 4;   // 16MB
    float* dxw3    = (float*)pool;               pool += (size_t)n * 4;       // 1MB
    float* out     = (float*)d_out;

    const int chunk = (E + G - 1) / G;

    // pass A: bin by src-tile (entA tile-major)
    k_acount<<<G, 1024, 0, stream>>>(src, acount, E, chunk, T);
    k_ascan <<<1, 256, 0, stream>>>(acount, tbase, E, T);
    k_afill <<<G, 1024, 0, stream>>>(src, dst, acount, entA, E, chunk, T);

    // pass B: bin tile-ordered stream by dst-bucket (order preserved ->
    // each bucket's entries grouped by src-tile)
    k_bcount<<<G, 1024, 0, stream>>>(entA, bcount, E, chunk);
    k_scan  <<<1, 1024, 0, stream>>>(bcount, colbase, E);
    k_bfill <<<G, 1024, 0, stream>>>(entA, tbase, bcount, ent, E, chunk, T);

    // degree + pre-scaled input (entA dead from here; pool reused)
    k_prep<<<K, 256, 0, stream>>>(ent, colbase, x, dinv, dx, n);

    // layers
    k_layer1<<<K, 512, 0, stream>>>(ent, colbase, dinv, dx, W1, b1, dh1, n);
    k_layer2<<<K, 256, 0, stream>>>(ent, colbase, dinv, dh1, W2, b2, W3, dxw3, n);
    k_out   <<<K, 512, 0, stream>>>(ent, colbase, dinv, dxw3, b3, out, n);
}